// Round 1
// baseline (129.989 us; speedup 1.0000x reference)
//
#include <hip/hip_runtime.h>
#include <math.h>

#define NPTS 4096
#define KNN  20
#define NOUT 64
#define WPB  2               // waves per block (barrier-free; packaging only)
#define QPW  4               // queries per wave
#define QBLK (WPB * QPW)     // 8 queries per block
#define BLKT (WPB * 64)      // 128 threads
#define PCAP 128             // per-query pool capacity == selection capacity
#define MITER 8              // max-pass iterations (2048-candidate sample)

// monotone float->uint map (total order preserved)
__device__ __forceinline__ unsigned ord32(float f) {
    unsigned u = __float_as_uint(f);
    int m = ((int)u) >> 31;
    return u ^ ((unsigned)m | 0x80000000u);
}
// inverse of ord32
__device__ __forceinline__ float iord32(unsigned r) {
    unsigned u = (r & 0x80000000u) ? (r ^ 0x80000000u) : ~r;
    return __uint_as_float(u);
}
__device__ __forceinline__ int mbcnt64(unsigned long long m) {
    return __builtin_amdgcn_mbcnt_hi((unsigned)(m >> 32),
           __builtin_amdgcn_mbcnt_lo((unsigned)m, 0));
}

// prologue: xq[b][j] = (x0, x1, x2, -(x0^2+x1^2+x2^2))
__global__ __launch_bounds__(256) void pack_kernel(const float* __restrict__ x,
                                                   float4* __restrict__ xq) {
    const int i = blockIdx.x * 256 + threadIdx.x;   // over B*NPTS
    const int b = i >> 12, j = i & (NPTS - 1);
    const float* xb = x + (size_t)b * 3 * NPTS;
    const float a0 = xb[j], a1 = xb[NPTS + j], a2 = xb[2 * NPTS + j];
    xq[i] = make_float4(a0, a1, a2, -fmaf(a0, a0, fmaf(a1, a1, a2 * a2)));
}

__global__ __launch_bounds__(BLKT, 8) void edgeconv_kernel(
    const float4* __restrict__ xq,    // (B, N) packed points
    const float* __restrict__ Wm,     // (64, 6)
    const float* __restrict__ gamma,
    const float* __restrict__ beta,
    const float* __restrict__ mean,
    const float* __restrict__ var,
    float* __restrict__ out)          // (B, 64, N)
{
    const int bid = blockIdx.x;
    const int b   = bid >> 9;                    // 512 blocks per batch
    const int n0  = (bid & 511) * QBLK;
    const int t    = threadIdx.x;
    const int lane = t & 63;
    const int w    = t >> 6;

    __shared__ unsigned long long pool[QBLK * PCAP];    // 8 KB, wave-private rows

    const float4* xqb = xq + (size_t)b * NPTS;

    // ---- query constants (uniform -> scalar loads) ----
    const int na = __builtin_amdgcn_readfirstlane(n0 + QPW * w);
    float q0[QPW], q1[QPW], q2[QPW];
    #pragma unroll
    for (int q = 0; q < QPW; ++q) {
        const float4 pv = xqb[na + q];
        q0[q] = 2.f * pv.x; q1[q] = 2.f * pv.y; q2[q] = 2.f * pv.z;
    }

    // ---- max pass: 2048-candidate sample, 2 lane-maxima groups per query ----
    // Rolled loops (I$-friendly); u/q inner loops stay unrolled so all arrays
    // are compile-time indexed (registers, not scratch).
    float vm0[QPW], vm1[QPW];
    #pragma unroll
    for (int q = 0; q < QPW; ++q) { vm0[q] = -INFINITY; vm1[q] = -INFINITY; }

    #pragma unroll 1
    for (int g = 0; g < MITER / 2; ++g) {               // candidates 0..1023
        float4 cc[4];
        #pragma unroll
        for (int u = 0; u < 4; ++u) cc[u] = xqb[(g * 4 + u) * 64 + lane];
        #pragma unroll
        for (int u = 0; u < 4; ++u) {
            #pragma unroll
            for (int q = 0; q < QPW; ++q) {
                const float e = fmaf(q0[q], cc[u].x, fmaf(q1[q], cc[u].y, fmaf(q2[q], cc[u].z, cc[u].w)));
                vm0[q] = fmaxf(vm0[q], e);
            }
        }
    }
    #pragma unroll 1
    for (int g = MITER / 2; g < MITER; ++g) {           // candidates 1024..2047
        float4 cc[4];
        #pragma unroll
        for (int u = 0; u < 4; ++u) cc[u] = xqb[(g * 4 + u) * 64 + lane];
        #pragma unroll
        for (int u = 0; u < 4; ++u) {
            #pragma unroll
            for (int q = 0; q < QPW; ++q) {
                const float e = fmaf(q0[q], cc[u].x, fmaf(q1[q], cc[u].y, fmaf(q2[q], cc[u].z, cc[u].w)));
                vm1[q] = fmaxf(vm1[q], e);
            }
        }
    }

    // ---- T[q] ~ 20th-largest of 128 group maxima (16-bit ballot bsearch) ----
    // The 20 top group-maxima are 20 distinct candidates >= T, so the true
    // 20th-best >= T => {all candidates >= T} is a superset of the exact
    // top-20. 16-bit truncation only lowers T (safe, slightly larger pool).
    // Rolled bit loop, 4 queries interleaved inside for ILP on the serial
    // ballot->popc->select chain.
    unsigned h0[QPW], h1[QPW], Kq[QPW];
    #pragma unroll
    for (int q = 0; q < QPW; ++q) {
        h0[q] = ord32(vm0[q]) >> 16;
        h1[q] = ord32(vm1[q]) >> 16;
        Kq[q] = 0;
    }
    #pragma unroll 1
    for (int bit = 15; bit >= 0; --bit) {
        #pragma unroll
        for (int q = 0; q < QPW; ++q) {
            const unsigned p = Kq[q] | (1u << bit);
            const int c = __popcll(__ballot(h0[q] >= p)) + __popcll(__ballot(h1[q] >= p));
            if (c >= KNN) Kq[q] = p;
        }
    }
    float Tf[QPW];
    #pragma unroll
    for (int q = 0; q < QPW; ++q) Tf[q] = iord32(Kq[q] << 16);

    const int invl = (NPTS - 1) - lane;

    // ---- filter pass: all 4096 candidates, ballot append (NO atomics) ----
    // Pool rows are wave-private: position = scalar count + mbcnt(ballot).
    // Counters live in SGPRs (ballot/popc results are uniform).
    int cq0 = 0, cq1 = 0, cq2 = 0, cq3 = 0;
    #pragma unroll 1
    for (int g = 0; g < NPTS / 256; ++g) {
        float4 cc[4];
        #pragma unroll
        for (int u = 0; u < 4; ++u) cc[u] = xqb[(g * 4 + u) * 64 + lane];
        #pragma unroll
        for (int u = 0; u < 4; ++u) {
            const unsigned tag = (unsigned)(invl - (g * 4 + u) * 64);
            float e4[QPW];
            #pragma unroll
            for (int q = 0; q < QPW; ++q)
                e4[q] = fmaf(q0[q], cc[u].x, fmaf(q1[q], cc[u].y, fmaf(q2[q], cc[u].z, cc[u].w)));
            #pragma unroll
            for (int q = 0; q < QPW; ++q) {
                const unsigned long long mask = __ballot(e4[q] >= Tf[q]);
                int* cqp = (q == 0) ? &cq0 : (q == 1) ? &cq1 : (q == 2) ? &cq2 : &cq3;
                if (mask) {                              // wave-uniform branch
                    const int pos = *cqp + mbcnt64(mask);
                    if (((mask >> lane) & 1) && pos < PCAP)
                        pool[(QPW * w + q) * PCAP + pos] =
                            ((unsigned long long)ord32(e4[q]) << 32) | tag;
                    *cqp += __popcll(mask);
                }
            }
        }
    }

    // ---- exact top-20 set per query: 32-bit ballot bsearch, 2 entries/lane ----
    // Wave-private pool; same-wave DS ops are in-order -> no barrier needed.
    // One rolled bit loop with all 4 queries interleaved.
    unsigned k0[QPW], k1[QPW], t0v[QPW], t1v[QPW], Ks[QPW];
    int cqa[QPW] = {cq0, cq1, cq2, cq3};
    #pragma unroll
    for (int q = 0; q < QPW; ++q) {
        int cw = cqa[q]; if (cw > PCAP) cw = PCAP;      // >= 20 guaranteed
        const unsigned long long* pl = pool + (size_t)(QPW * w + q) * PCAP;
        // sentinel 0: ord32(finite) >= 1, so pad entries never counted
        const unsigned long long e0 = (lane < cw) ? pl[lane] : 0ull;
        const unsigned long long e1 = (lane + 64 < cw) ? pl[lane + 64] : 0ull;
        k0[q] = (unsigned)(e0 >> 32); t0v[q] = (unsigned)e0;
        k1[q] = (unsigned)(e1 >> 32); t1v[q] = (unsigned)e1;
        Ks[q] = 0;
    }
    #pragma unroll 1
    for (int bit = 31; bit >= 0; --bit) {
        #pragma unroll
        for (int q = 0; q < QPW; ++q) {
            const unsigned p = Ks[q] | (1u << bit);
            const int c = __popcll(__ballot(k0[q] >= p)) + __popcll(__ballot(k1[q] >= p));
            if (c >= KNN) Ks[q] = p;
        }
    }

    unsigned myidx[QPW];
    #pragma unroll
    for (int q = 0; q < QPW; ++q) {
        unsigned long long g0 = __ballot(k0[q] > Ks[q]);
        unsigned long long g1 = __ballot(k1[q] > Ks[q]);
        const int m = __popcll(g0) + __popcll(g1);     // <= 19
        unsigned long long s0 = __ballot(k0[q] == Ks[q]);
        unsigned long long s1 = __ballot(k1[q] == Ks[q]);
        const int r = KNN - m;                         // >= 1 ties needed
        if (__popcll(s0) + __popcll(s1) > r) {
            // tie split: choose r ties with largest tag (= lowest index)
            unsigned TT = 0;
            #pragma unroll 1
            for (int bit = 11; bit >= 0; --bit) {      // tags < 4096
                const unsigned p = TT | (1u << bit);
                const int c = __popcll(__ballot(k0[q] == Ks[q] && t0v[q] >= p)) +
                              __popcll(__ballot(k1[q] == Ks[q] && t1v[q] >= p));
                if (c >= r) TT = p;
            }
            s0 = __ballot(k0[q] == Ks[q] && t0v[q] >= TT);
            s1 = __ballot(k1[q] == Ks[q] && t1v[q] >= TT);
        }

        unsigned* idxq = (unsigned*)(pool + (size_t)(QPW * w + q) * PCAP); // alias consumed pool
        if ((g0 >> lane) & 1) idxq[mbcnt64(g0)] = t0v[q];
        if ((g1 >> lane) & 1) idxq[__popcll(g0) + mbcnt64(g1)] = t1v[q];
        if ((s0 >> lane) & 1) idxq[m + mbcnt64(s0)] = t0v[q];
        if ((s1 >> lane) & 1) idxq[m + __popcll(s0) + mbcnt64(s1)] = t1v[q];
        myidx[q] = idxq[(lane < KNN) ? lane : 0];
    }

    // ---- epilogue: lane = output channel; neighbors via scalar loads ----
    // Chunked by 4 so four s_load_dwordx4 are in flight per step instead of
    // one fully-serial readlane->s_load->use chain per neighbor.
    const int o = lane;
    const float iv   = gamma[o] / sqrtf(var[o] + 1e-5f);
    const float bias = beta[o] - mean[o] * iv;
    const float* Wr = Wm + o * 6;
    const float w0p = Wr[0] * iv, w1p = Wr[1] * iv, w2p = Wr[2] * iv;
    const float w3p = Wr[3] * iv, w4p = Wr[4] * iv, w5p = Wr[5] * iv;

    float bests[QPW];
    #pragma unroll
    for (int q = 0; q < QPW; ++q) {
        const float4 pv = xqb[na + q];                 // scalar reload
        const float basep = fmaf(w3p, pv.x, fmaf(w4p, pv.y, fmaf(w5p, pv.z, bias)));
        const float base2 = basep - fmaf(w0p, pv.x, fmaf(w1p, pv.y, w2p * pv.z));
        float best = -INFINITY;
        #pragma unroll 1
        for (int kc = 0; kc < KNN; kc += 4) {
            float4 f[4];
            #pragma unroll
            for (int j = 0; j < 4; ++j) {
                const int lk = __builtin_amdgcn_readlane((int)myidx[q], kc + j);
                const int gi = __builtin_amdgcn_readfirstlane((NPTS - 1) - lk);
                f[j] = xqb[gi];                        // s_load_dwordx4
            }
            #pragma unroll
            for (int j = 0; j < 4; ++j) {
                float y = fmaf(w0p, f[j].x, fmaf(w1p, f[j].y, fmaf(w2p, f[j].z, base2)));
                y = fmaxf(y, 0.2f * y);                // LeakyReLU
                best = fmaxf(best, y);
            }
        }
        bests[q] = best;
    }

    // ---- direct store: lane o writes its 4 consecutive n's as one float4 ----
    float4 res;
    res.x = bests[0]; res.y = bests[1]; res.z = bests[2]; res.w = bests[3];
    *(float4*)(out + ((size_t)b * NOUT + o) * NPTS + na) = res;
}

extern "C" void kernel_launch(void* const* d_in, const int* in_sizes, int n_in,
                              void* d_out, int out_size, void* d_ws, size_t ws_size,
                              hipStream_t stream) {
    const float* x     = (const float*)d_in[0];
    const float* Wm    = (const float*)d_in[1];
    const float* gamma = (const float*)d_in[2];
    const float* beta  = (const float*)d_in[3];
    const float* mean  = (const float*)d_in[4];
    const float* var   = (const float*)d_in[5];
    float* out = (float*)d_out;
    float4* xq = (float4*)d_ws;                    // B*NPTS float4 = 512 KB

    const int B = in_sizes[0] / (3 * NPTS);        // 8
    pack_kernel<<<B * NPTS / 256, 256, 0, stream>>>(x, xq);
    const int nblocks = B * (NPTS / QBLK);         // 8 * 512 = 4096
    edgeconv_kernel<<<nblocks, BLKT, 0, stream>>>(xq, Wm, gamma, beta, mean, var, out);
}